// Round 5
// baseline (385.783 us; speedup 1.0000x reference)
//
#include <hip/hip_runtime.h>
#include <hip/hip_bf16.h>
#include <stdint.h>

#define Sq   2048
#define Dq   256
#define Hq   8
#define NQKV 6144          // 3*H*D
#define HD   2048          // H*D
#define MTOK 8192          // B*S

typedef __attribute__((ext_vector_type(8))) short short8;
typedef __attribute__((ext_vector_type(4))) float f32x4;
typedef __attribute__((ext_vector_type(16))) float f32x16;
typedef __attribute__((ext_vector_type(4))) int i32x4;

__device__ __forceinline__ float bf2f(short v) {
  union { float f; unsigned u; } x; x.u = ((unsigned)(unsigned short)v) << 16; return x.f;
}
__device__ __forceinline__ short f2bf(float f) {
  union { float f; unsigned u; } x; x.f = f;
  unsigned r = x.u + 0x7fffu + ((x.u >> 16) & 1u);
  return (short)(r >> 16);
}
// global -> LDS direct (16B per lane); LDS dest is wave-uniform base + lane*16
__device__ __forceinline__ void gload16(const void* g, void* lds) {
  auto g1 = (const __attribute__((address_space(1))) int*)(uintptr_t)g;
  auto l3 = (__attribute__((address_space(3))) int*)(uintptr_t)lds;
  __builtin_amdgcn_global_load_lds(g1, l3, 16, 0, 0);
}
__device__ __forceinline__ float exp2a(float x) {   // D = 2^x
  float r; asm("v_exp_f32 %0, %1" : "=v"(r) : "v"(x)); return r;
}
__device__ __forceinline__ unsigned cvtpk(float lo, float hi) {
  unsigned r; asm("v_cvt_pk_bf16_f32 %0, %1, %2" : "=v"(r) : "v"(lo), "v"(hi)); return r;
}
__device__ __forceinline__ void plswap(unsigned &a, unsigned &b) {
  asm volatile("v_permlane32_swap_b32 %0, %1" : "+v"(a), "+v"(b));
}
__device__ __forceinline__ f32x16 fz16() {
  f32x16 z;
#pragma unroll
  for (int e = 0; e < 16; e++) z[e] = 0.f;
  return z;
}

// ---------------- prep: bf16 converts + rope tables (fp32 math) ----------------
__global__ __launch_bounds__(256) void k_prep(
    const float* __restrict__ x, const float* __restrict__ wqkv,
    const float* __restrict__ wout,
    short* __restrict__ xb, short* __restrict__ wqb, short* __restrict__ wob,
    float* __restrict__ cost, float* __restrict__ sint)
{
  long i = (long)blockIdx.x * 256 + threadIdx.x;
  const long n_x  = (long)MTOK * Dq;     // 2097152
  const long n_wq = (long)NQKV * Dq;     // 1572864
  const long n_wo = (long)Dq * HD;       // 524288
  const long n_tab = (long)Sq * 128;     // 262144
  if (i < n_x) { xb[i] = f2bf(x[i]); return; }
  i -= n_x;
  if (i < n_wq) { wqb[i] = f2bf(wqkv[i]); return; }
  i -= n_wq;
  if (i < n_wo) { wob[i] = f2bf(wout[i]); return; }
  i -= n_wo;
  if (i < n_tab) {
    int s = (int)(i >> 7), j = (int)(i & 127);
    float inv = __expf(-(float)j * (9.2103403720f / 128.0f));  // 10000^(-j/128)
    float a = (float)s * inv;
    cost[i] = cosf(a);
    sint[i] = sinf(a);
  }
}

// ---------------- GEMM: C[M,N] = A[M,K] * Bt[N,K]^T + bias (+resid) ----------------
// EPI 0: write bf16.  EPI 1: write fp32 + resid.  BN: 128 or 64.
template<int EPI, int BN>
__global__ __launch_bounds__(256, 2) void k_gemm(
    const short* __restrict__ A, const short* __restrict__ Bt,
    const float* __restrict__ bias, const float* __restrict__ resid,
    void* __restrict__ Cp, int M, int N, int K)
{
  constexpr int MI = (BN == 128) ? 4 : 2;   // 16-row tiles per wave
  constexpr int WRS = MI * 16;              // wave row span
  constexpr int BROUNDS = BN / 32;
  __shared__ short As[128 * 64];
  __shared__ short Bs[BN * 64];
  const int tid = threadIdx.x;
  const int w = tid >> 6, lane = tid & 63;
  const int grp = lane >> 4, l15 = lane & 15;
  const int wr = (BN == 128) ? (w >> 1) : w;
  const int wc = (BN == 128) ? (w & 1) : 0;
  const int m0 = blockIdx.y * 128, n0 = blockIdx.x * BN;

  f32x4 acc[MI][4];
#pragma unroll
  for (int i = 0; i < MI; i++)
#pragma unroll
    for (int j = 0; j < 4; j++) acc[i][j] = f32x4{0.f, 0.f, 0.f, 0.f};

  for (int kt = 0; kt < K; kt += 64) {
#pragma unroll
    for (int r = 0; r < 4; r++) {
      int G = r * 256 + tid;
      int row = G >> 3, gc = G & 7;
      gload16(A + (size_t)(m0 + row) * K + kt + gc * 8,
              (char*)As + (r * 256 + w * 64) * 16);
    }
#pragma unroll
    for (int r = 0; r < BROUNDS; r++) {
      int G = r * 256 + tid;
      int row = G >> 3, gc = G & 7;
      gload16(Bt + (size_t)(n0 + row) * K + kt + gc * 8,
              (char*)Bs + (r * 256 + w * 64) * 16);
    }
    __syncthreads();
#pragma unroll
    for (int kk = 0; kk < 2; kk++) {
      short8 af[MI], bf[4];
#pragma unroll
      for (int mi = 0; mi < MI; mi++) {
        int row = wr * WRS + mi * 16 + l15;
        af[mi] = *(const short8*)&As[row * 64 + kk * 32 + grp * 8];
      }
#pragma unroll
      for (int ni = 0; ni < 4; ni++) {
        int row = wc * 64 + ni * 16 + l15;
        bf[ni] = *(const short8*)&Bs[row * 64 + kk * 32 + grp * 8];
      }
#pragma unroll
      for (int mi = 0; mi < MI; mi++)
#pragma unroll
        for (int ni = 0; ni < 4; ni++)
          acc[mi][ni] = __builtin_amdgcn_mfma_f32_16x16x32_bf16(
              af[mi], bf[ni], acc[mi][ni], 0, 0, 0);
    }
    __syncthreads();
  }
#pragma unroll
  for (int mi = 0; mi < MI; mi++) {
#pragma unroll
    for (int ni = 0; ni < 4; ni++) {
      int colb = n0 + wc * 64 + ni * 16 + l15;
      float bv = bias[colb];
#pragma unroll
      for (int j = 0; j < 4; j++) {
        int row = m0 + wr * WRS + mi * 16 + grp * 4 + j;
        float v = acc[mi][ni][j] + bv;
        if (EPI == 0) {
          ((short*)Cp)[(size_t)row * N + colb] = f2bf(v);
        } else {
          size_t o = (size_t)row * N + colb;
          ((float*)Cp)[o] = v + resid[o];
        }
      }
    }
  }
}

// ---------------- RoPE in-place on q,k (q scaled by log2e/16) ----------------
__global__ __launch_bounds__(256) void k_rope(
    short* __restrict__ qkv, const float* __restrict__ cost,
    const float* __restrict__ sint)
{
  int id = blockIdx.x * 256 + threadIdx.x;   // 1048576 total
  int jv = id & 15;
  int h = (id >> 4) & 7;
  int t = id >> 7;                           // 0..8191 (= b*S+s)
  int s = t & (Sq - 1);
  const float QS = 0.090168441f;             // (1/16) * log2(e)
  size_t base = (size_t)t * NQKV + h * 256 + jv * 8;
  short8 q1 = *(const short8*)&qkv[base];
  short8 q2 = *(const short8*)&qkv[base + 128];
  short8 k1 = *(const short8*)&qkv[base + 2048];
  short8 k2 = *(const short8*)&qkv[base + 2048 + 128];
  const float* cp = &cost[(size_t)s * 128 + jv * 8];
  const float* sp = &sint[(size_t)s * 128 + jv * 8];
  short8 oq1, oq2, ok1, ok2;
#pragma unroll
  for (int e = 0; e < 8; e++) {
    float c = cp[e], sn = sp[e];
    float a = bf2f(q1[e]), b2 = bf2f(q2[e]);
    oq1[e] = f2bf((a * c - b2 * sn) * QS);
    oq2[e] = f2bf((a * sn + b2 * c) * QS);
    float ka = bf2f(k1[e]), kb = bf2f(k2[e]);
    ok1[e] = f2bf(ka * c - kb * sn);
    ok2[e] = f2bf(ka * sn + kb * c);
  }
  *(short8*)&qkv[base] = oq1;
  *(short8*)&qkv[base + 128] = oq2;
  *(short8*)&qkv[base + 2048] = ok1;
  *(short8*)&qkv[base + 2048 + 128] = ok2;
}

// ---------------- V transpose: vT[bh][d][s] = v[b,s,h,d] ----------------
__global__ __launch_bounds__(256) void k_vt(
    const short* __restrict__ qkv, short* __restrict__ vT)
{
  __shared__ short t[64][72];
  int kt = blockIdx.x, dt = blockIdx.y, bh = blockIdx.z;
  int b = bh >> 3, h = bh & 7;
  int tid = threadIdx.x;
  int r = tid >> 2, c0 = (tid & 3) * 16;
  const short* src = &qkv[(size_t)(b * Sq + kt * 64 + r) * NQKV + 4096 + h * 256 + dt * 64 + c0];
  short8 v0 = *(const short8*)src;
  short8 v1 = *(const short8*)(src + 8);
#pragma unroll
  for (int e = 0; e < 8; e++) { t[r][c0 + e] = v0[e]; t[r][c0 + 8 + e] = v1[e]; }
  __syncthreads();
  short8 o0, o1;
#pragma unroll
  for (int e = 0; e < 8; e++) { o0[e] = t[c0 + e][r]; o1[e] = t[c0 + 8 + e][r]; }
  short* dst = &vT[(size_t)(bh * 256 + dt * 64 + r) * Sq + kt * 64 + c0];
  *(short8*)dst = o0;
  *(short8*)(dst + 8) = o1;
}

// ---------------- flash attention: 32x32 MFMA, dbuf prefetch pipeline --------
// 1D grid 512; 4 waves x 32 q-rows = 128 q-rows/block. KV tile = 32 keys.
__global__ __launch_bounds__(256, 2) void k_attn(
    const short* __restrict__ qkv, const short* __restrict__ vT,
    short* __restrict__ attn)
{
  __shared__ short Ks[2][32 * 256];   // [buf][key][d], granule-swizzled  (32 KB)
  __shared__ short Vs[2][256 * 36];   // [buf][d][key], padded 32->36     (36 KB)
  const int tid = threadIdx.x;
  const int w = tid >> 6, lane = tid & 63;
  const int l31 = lane & 31, hi = lane >> 5;
  const int id = blockIdx.x;
  // XCD-aware remap: 4 heads per XCD (id%8 ~ XCD under round-robin dispatch)
  const int bh = (id & 7) * 4 + ((id >> 3) & 3);
  const int qb0 = (id >> 5) * 128;
  const int b = bh >> 3, h = bh & 7;

  // Q as B-fragments: lane holds Q[qrow=l31][d = kc*16 + hi*8 + e]
  short8 qf[16];
  {
    const short* qbase = &qkv[(size_t)(b * Sq + qb0 + w * 32 + l31) * NQKV + h * 256 + hi * 8];
#pragma unroll
    for (int kc = 0; kc < 16; kc++) qf[kc] = *(const short8*)&qbase[kc * 16];
  }
  f32x16 o[8];
#pragma unroll
  for (int dt = 0; dt < 8; dt++) o[dt] = fz16();
  float m = -3e38f, l = 0.f;

  const size_t krow0 = (size_t)(b * Sq) * NQKV + 2048 + h * 256;
  const short* vbase = &vT[(size_t)bh * 256 * Sq];

  // ---- prologue: stage tile 0 ----
#pragma unroll
  for (int r = 0; r < 4; r++) {
    int G = r * 256 + tid;
    int row = G >> 5, gc = G & 31;
    gload16(&qkv[krow0 + (size_t)row * NQKV + ((gc ^ (row & 7)) * 8)],
            (char*)&Ks[0][0] + (r * 256 + w * 64) * 16);
  }
  {
    short8 v0[4];
#pragma unroll
    for (int r = 0; r < 4; r++) {
      int G = r * 256 + tid;
      v0[r] = *(const short8*)&vbase[(size_t)(G >> 2) * Sq + (G & 3) * 8];
    }
#pragma unroll
    for (int r = 0; r < 4; r++) {
      int G = r * 256 + tid;
      *(short8*)&Vs[0][(G >> 2) * 36 + (G & 3) * 8] = v0[r];
    }
  }
  __syncthreads();

  int cur = 0;
  for (int kt = 0; kt < Sq / 32; kt++) {
    // ---- issue next tile's loads (K -> LDS[cur^1] direct, V -> regs) ----
    short8 vnext[4];
    if (kt + 1 < Sq / 32) {
#pragma unroll
      for (int r = 0; r < 4; r++) {
        int G = r * 256 + tid;
        int row = G >> 5, gc = G & 31;
        gload16(&qkv[krow0 + (size_t)((kt + 1) * 32 + row) * NQKV + ((gc ^ (row & 7)) * 8)],
                (char*)&Ks[cur ^ 1][0] + (r * 256 + w * 64) * 16);
      }
#pragma unroll
      for (int r = 0; r < 4; r++) {
        int G = r * 256 + tid;
        vnext[r] = *(const short8*)&vbase[(size_t)(G >> 2) * Sq + (kt + 1) * 32 + (G & 3) * 8];
      }
    }

    // ---- QK^T (swapped): 2 interleaved partial accumulators break the
    //      16-deep dependent MFMA chain into two 8-chains ----
    f32x16 s0 = fz16(), s1 = fz16();
    __builtin_amdgcn_s_setprio(1);
#define QKSTEP(KC, SACC) { \
      int byteoff = l31 * 512 + ((((KC) * 2 + hi) ^ (l31 & 7)) << 4); \
      short8 ka = *(const short8*)((const char*)&Ks[cur][0] + byteoff); \
      SACC = __builtin_amdgcn_mfma_f32_32x32x16_bf16(ka, qf[KC], SACC, 0, 0, 0); }
    QKSTEP(0, s0)  QKSTEP(1, s1)  QKSTEP(2, s0)  QKSTEP(3, s1)
    QKSTEP(4, s0)  QKSTEP(5, s1)  QKSTEP(6, s0)  QKSTEP(7, s1)
    QKSTEP(8, s0)  QKSTEP(9, s1)  QKSTEP(10, s0) QKSTEP(11, s1)
    QKSTEP(12, s0) QKSTEP(13, s1) QKSTEP(14, s0) QKSTEP(15, s1)
#undef QKSTEP
    __builtin_amdgcn_s_setprio(0);
    f32x16 sc = s0 + s1;

    // ---- online softmax, in-register (scores in log2 domain) ----
    float t8[8];
#pragma unroll
    for (int e = 0; e < 8; e++) t8[e] = fmaxf(sc[e], sc[e + 8]);
#pragma unroll
    for (int e = 0; e < 4; e++) t8[e] = fmaxf(t8[e], t8[e + 4]);
    t8[0] = fmaxf(t8[0], t8[2]); t8[1] = fmaxf(t8[1], t8[3]);
    float pmax = fmaxf(t8[0], t8[1]);
    pmax = fmaxf(pmax, __shfl_xor(pmax, 32, 64));
    if (!__all(pmax <= m + 8.0f)) {          // defer-max (THR=8, log2 domain)
      float nm = fmaxf(m, pmax);
      float f = exp2a(m - nm);
      l *= f;
#pragma unroll
      for (int dt = 0; dt < 8; dt++)
#pragma unroll
        for (int e = 0; e < 16; e++) o[dt][e] *= f;
      m = nm;
    }
#pragma unroll
    for (int e = 0; e < 16; e++) sc[e] = exp2a(sc[e] - m);
    float r8[8];
#pragma unroll
    for (int e = 0; e < 8; e++) r8[e] = sc[e] + sc[e + 8];
#pragma unroll
    for (int e = 0; e < 4; e++) r8[e] = r8[e] + r8[e + 4];
    r8[0] += r8[2]; r8[1] += r8[3];
    float rs = r8[0] + r8[1];
    rs += __shfl_xor(rs, 32, 64);
    l += rs;

    // ---- P -> PV A-fragments in-register (cvt_pk + permlane32_swap) ----
    short8 pa[2];
    {
      unsigned x0 = cvtpk(sc[0], sc[1]);
      unsigned y0 = cvtpk(sc[4], sc[5]);
      unsigned x1 = cvtpk(sc[2], sc[3]);
      unsigned y1 = cvtpk(sc[6], sc[7]);
      plswap(x0, y0);
      plswap(x1, y1);
      i32x4 w0; w0[0] = x0; w0[1] = x1; w0[2] = y0; w0[3] = y1;
      pa[0] = __builtin_bit_cast(short8, w0);
      unsigned x2 = cvtpk(sc[8],  sc[9]);
      unsigned y2 = cvtpk(sc[12], sc[13]);
      unsigned x3 = cvtpk(sc[10], sc[11]);
      unsigned y3 = cvtpk(sc[14], sc[15]);
      plswap(x2, y2);
      plswap(x3, y3);
      i32x4 w1; w1[0] = x2; w1[1] = x3; w1[2] = y2; w1[3] = y3;
      pa[1] = __builtin_bit_cast(short8, w1);
    }

    // ---- PV: o[dt] += P . V  (8 independent 2-chains) ----
    __builtin_amdgcn_s_setprio(1);
#pragma unroll
    for (int dt = 0; dt < 8; dt++) {
#pragma unroll
      for (int ks = 0; ks < 2; ks++) {
        short8 vb = *(const short8*)&Vs[cur][(dt * 32 + l31) * 36 + ks * 16 + hi * 8];
        o[dt] = __builtin_amdgcn_mfma_f32_32x32x16_bf16(pa[ks], vb, o[dt], 0, 0, 0);
      }
    }
    __builtin_amdgcn_s_setprio(0);

    // ---- write prefetched V into LDS[cur^1], then single barrier ----
    if (kt + 1 < Sq / 32) {
#pragma unroll
      for (int r = 0; r < 4; r++) {
        int G = r * 256 + tid;
        *(short8*)&Vs[cur ^ 1][(G >> 2) * 36 + (G & 3) * 8] = vnext[r];
      }
    }
    __syncthreads();
    cur ^= 1;
  }

  // ---- finalize: /l, store bf16 ----
  float linv = 1.0f / l;
  float li[16];
#pragma unroll
  for (int e = 0; e < 16; e++)
    li[e] = __shfl(linv, (e & 3) + 8 * (e >> 2) + 4 * hi, 64);
  short* orow = &attn[(size_t)(b * Sq + qb0 + w * 32) * HD + h * 256 + l31];
#pragma unroll
  for (int dt = 0; dt < 8; dt++)
#pragma unroll
    for (int e = 0; e < 16; e++)
      orow[(size_t)((e & 3) + 8 * (e >> 2) + 4 * hi) * HD + dt * 32] = f2bf(o[dt][e] * li[e]);
}

// ---------------- launch ----------------
extern "C" void kernel_launch(void* const* d_in, const int* in_sizes, int n_in,
                              void* d_out, int out_size, void* d_ws, size_t ws_size,
                              hipStream_t stream) {
  const float* x     = (const float*)d_in[0];
  const float* w_qkv = (const float*)d_in[1];
  const float* b_qkv = (const float*)d_in[2];
  const float* w_out = (const float*)d_in[3];
  const float* b_out = (const float*)d_in[4];
  float* out = (float*)d_out;

  char* ws = (char*)d_ws;
  short* qkv  = (short*)ws;                               // 100663296 B
  short* vT   = (short*)(ws + 100663296);                 // 33554432 B
  short* attn = (short*)(ws + 134217728);                 // 33554432 B
  short* xb   = (short*)(ws + 167772160);                 // 4194304 B
  short* wqb  = (short*)(ws + 171966464);                 // 3145728 B
  short* wob  = (short*)(ws + 175112192);                 // 1048576 B
  float* cost = (float*)(ws + 176160768);                 // 1048576 B
  float* sint = (float*)(ws + 177209344);                 // 1048576 B

  k_prep<<<dim3(17408), 256, 0, stream>>>(x, w_qkv, w_out, xb, wqb, wob, cost, sint);
  k_gemm<0, 128><<<dim3(NQKV / 128, MTOK / 128), 256, 0, stream>>>(
      xb, wqb, b_qkv, nullptr, qkv, MTOK, NQKV, Dq);
  k_rope<<<dim3(4096), 256, 0, stream>>>(qkv, cost, sint);
  k_vt<<<dim3(32, 4, 32), 256, 0, stream>>>(qkv, vT);
  k_attn<<<dim3(512), 256, 0, stream>>>(qkv, vT, attn);
  k_gemm<1, 64><<<dim3(Dq / 64, MTOK / 128), 256, 0, stream>>>(
      attn, wob, b_out, x, out, MTOK, Dq, HD);
}

// Round 6
// 340.488 us; speedup vs baseline: 1.1330x; 1.1330x over previous
//
#include <hip/hip_runtime.h>
#include <hip/hip_bf16.h>
#include <stdint.h>

#define Sq   2048
#define Dq   256
#define Hq   8
#define NQKV 6144          // 3*H*D
#define HD   2048          // H*D
#define MTOK 8192          // B*S

typedef __attribute__((ext_vector_type(8))) short short8;
typedef __attribute__((ext_vector_type(4))) float f32x4;
typedef __attribute__((ext_vector_type(16))) float f32x16;
typedef __attribute__((ext_vector_type(4))) int i32x4;

__device__ __forceinline__ float bf2f(short v) {
  union { float f; unsigned u; } x; x.u = ((unsigned)(unsigned short)v) << 16; return x.f;
}
__device__ __forceinline__ short f2bf(float f) {
  union { float f; unsigned u; } x; x.f = f;
  unsigned r = x.u + 0x7fffu + ((x.u >> 16) & 1u);
  return (short)(r >> 16);
}
// global -> LDS direct (16B per lane); LDS dest is wave-uniform base + lane*16
__device__ __forceinline__ void gload16(const void* g, void* lds) {
  auto g1 = (const __attribute__((address_space(1))) int*)(uintptr_t)g;
  auto l3 = (__attribute__((address_space(3))) int*)(uintptr_t)lds;
  __builtin_amdgcn_global_load_lds(g1, l3, 16, 0, 0);
}
__device__ __forceinline__ float exp2a(float x) {   // D = 2^x
  float r; asm("v_exp_f32 %0, %1" : "=v"(r) : "v"(x)); return r;
}
__device__ __forceinline__ unsigned cvtpk(float lo, float hi) {
  unsigned r; asm("v_cvt_pk_bf16_f32 %0, %1, %2" : "=v"(r) : "v"(lo), "v"(hi)); return r;
}
__device__ __forceinline__ void plswap(unsigned &a, unsigned &b) {
  asm volatile("v_permlane32_swap_b32 %0, %1" : "+v"(a), "+v"(b));
}
__device__ __forceinline__ f32x16 fz16() {
  f32x16 z;
#pragma unroll
  for (int e = 0; e < 16; e++) z[e] = 0.f;
  return z;
}

// ---------------- prep: bf16 converts + rope tables (fp32 math) ----------------
__global__ __launch_bounds__(256) void k_prep(
    const float* __restrict__ x, const float* __restrict__ wqkv,
    const float* __restrict__ wout,
    short* __restrict__ xb, short* __restrict__ wqb, short* __restrict__ wob,
    float* __restrict__ cost, float* __restrict__ sint)
{
  long i = (long)blockIdx.x * 256 + threadIdx.x;
  const long n_x  = (long)MTOK * Dq;     // 2097152
  const long n_wq = (long)NQKV * Dq;     // 1572864
  const long n_wo = (long)Dq * HD;       // 524288
  const long n_tab = (long)Sq * 128;     // 262144
  if (i < n_x) { xb[i] = f2bf(x[i]); return; }
  i -= n_x;
  if (i < n_wq) { wqb[i] = f2bf(wqkv[i]); return; }
  i -= n_wq;
  if (i < n_wo) { wob[i] = f2bf(wout[i]); return; }
  i -= n_wo;
  if (i < n_tab) {
    int s = (int)(i >> 7), j = (int)(i & 127);
    float inv = __expf(-(float)j * (9.2103403720f / 128.0f));  // 10000^(-j/128)
    float a = (float)s * inv;
    cost[i] = cosf(a);
    sint[i] = sinf(a);
  }
}

// ---------------- GEMM: C[M,N] = A[M,K] * Bt[N,K]^T + bias (+resid) ----------------
// EPI 0: write bf16.  EPI 1: write fp32 + resid.  BN: 128 or 64.
template<int EPI, int BN>
__global__ __launch_bounds__(256, 2) void k_gemm(
    const short* __restrict__ A, const short* __restrict__ Bt,
    const float* __restrict__ bias, const float* __restrict__ resid,
    void* __restrict__ Cp, int M, int N, int K)
{
  constexpr int MI = (BN == 128) ? 4 : 2;   // 16-row tiles per wave
  constexpr int WRS = MI * 16;              // wave row span
  constexpr int BROUNDS = BN / 32;
  __shared__ short As[128 * 64];
  __shared__ short Bs[BN * 64];
  const int tid = threadIdx.x;
  const int w = tid >> 6, lane = tid & 63;
  const int grp = lane >> 4, l15 = lane & 15;
  const int wr = (BN == 128) ? (w >> 1) : w;
  const int wc = (BN == 128) ? (w & 1) : 0;
  const int m0 = blockIdx.y * 128, n0 = blockIdx.x * BN;

  f32x4 acc[MI][4];
#pragma unroll
  for (int i = 0; i < MI; i++)
#pragma unroll
    for (int j = 0; j < 4; j++) acc[i][j] = f32x4{0.f, 0.f, 0.f, 0.f};

  for (int kt = 0; kt < K; kt += 64) {
#pragma unroll
    for (int r = 0; r < 4; r++) {
      int G = r * 256 + tid;
      int row = G >> 3, gc = G & 7;
      gload16(A + (size_t)(m0 + row) * K + kt + gc * 8,
              (char*)As + (r * 256 + w * 64) * 16);
    }
#pragma unroll
    for (int r = 0; r < BROUNDS; r++) {
      int G = r * 256 + tid;
      int row = G >> 3, gc = G & 7;
      gload16(Bt + (size_t)(n0 + row) * K + kt + gc * 8,
              (char*)Bs + (r * 256 + w * 64) * 16);
    }
    __syncthreads();
#pragma unroll
    for (int kk = 0; kk < 2; kk++) {
      short8 af[MI], bf[4];
#pragma unroll
      for (int mi = 0; mi < MI; mi++) {
        int row = wr * WRS + mi * 16 + l15;
        af[mi] = *(const short8*)&As[row * 64 + kk * 32 + grp * 8];
      }
#pragma unroll
      for (int ni = 0; ni < 4; ni++) {
        int row = wc * 64 + ni * 16 + l15;
        bf[ni] = *(const short8*)&Bs[row * 64 + kk * 32 + grp * 8];
      }
#pragma unroll
      for (int mi = 0; mi < MI; mi++)
#pragma unroll
        for (int ni = 0; ni < 4; ni++)
          acc[mi][ni] = __builtin_amdgcn_mfma_f32_16x16x32_bf16(
              af[mi], bf[ni], acc[mi][ni], 0, 0, 0);
    }
    __syncthreads();
  }
#pragma unroll
  for (int mi = 0; mi < MI; mi++) {
#pragma unroll
    for (int ni = 0; ni < 4; ni++) {
      int colb = n0 + wc * 64 + ni * 16 + l15;
      float bv = bias[colb];
#pragma unroll
      for (int j = 0; j < 4; j++) {
        int row = m0 + wr * WRS + mi * 16 + grp * 4 + j;
        float v = acc[mi][ni][j] + bv;
        if (EPI == 0) {
          ((short*)Cp)[(size_t)row * N + colb] = f2bf(v);
        } else {
          size_t o = (size_t)row * N + colb;
          ((float*)Cp)[o] = v + resid[o];
        }
      }
    }
  }
}

// ---------------- RoPE in-place on q,k (q scaled by log2e/16) ----------------
__global__ __launch_bounds__(256) void k_rope(
    short* __restrict__ qkv, const float* __restrict__ cost,
    const float* __restrict__ sint)
{
  int id = blockIdx.x * 256 + threadIdx.x;   // 1048576 total
  int jv = id & 15;
  int h = (id >> 4) & 7;
  int t = id >> 7;                           // 0..8191 (= b*S+s)
  int s = t & (Sq - 1);
  const float QS = 0.090168441f;             // (1/16) * log2(e)
  size_t base = (size_t)t * NQKV + h * 256 + jv * 8;
  short8 q1 = *(const short8*)&qkv[base];
  short8 q2 = *(const short8*)&qkv[base + 128];
  short8 k1 = *(const short8*)&qkv[base + 2048];
  short8 k2 = *(const short8*)&qkv[base + 2048 + 128];
  const float* cp = &cost[(size_t)s * 128 + jv * 8];
  const float* sp = &sint[(size_t)s * 128 + jv * 8];
  short8 oq1, oq2, ok1, ok2;
#pragma unroll
  for (int e = 0; e < 8; e++) {
    float c = cp[e], sn = sp[e];
    float a = bf2f(q1[e]), b2 = bf2f(q2[e]);
    oq1[e] = f2bf((a * c - b2 * sn) * QS);
    oq2[e] = f2bf((a * sn + b2 * c) * QS);
    float ka = bf2f(k1[e]), kb = bf2f(k2[e]);
    ok1[e] = f2bf(ka * c - kb * sn);
    ok2[e] = f2bf(ka * sn + kb * c);
  }
  *(short8*)&qkv[base] = oq1;
  *(short8*)&qkv[base + 128] = oq2;
  *(short8*)&qkv[base + 2048] = ok1;
  *(short8*)&qkv[base + 2048 + 128] = ok2;
}

// ---------------- V transpose: vT[bh][d][s] = v[b,s,h,d] ----------------
__global__ __launch_bounds__(256) void k_vt(
    const short* __restrict__ qkv, short* __restrict__ vT)
{
  __shared__ short t[64][72];
  int kt = blockIdx.x, dt = blockIdx.y, bh = blockIdx.z;
  int b = bh >> 3, h = bh & 7;
  int tid = threadIdx.x;
  int r = tid >> 2, c0 = (tid & 3) * 16;
  const short* src = &qkv[(size_t)(b * Sq + kt * 64 + r) * NQKV + 4096 + h * 256 + dt * 64 + c0];
  short8 v0 = *(const short8*)src;
  short8 v1 = *(const short8*)(src + 8);
#pragma unroll
  for (int e = 0; e < 8; e++) { t[r][c0 + e] = v0[e]; t[r][c0 + 8 + e] = v1[e]; }
  __syncthreads();
  short8 o0, o1;
#pragma unroll
  for (int e = 0; e < 8; e++) { o0[e] = t[c0 + e][r]; o1[e] = t[c0 + 8 + e][r]; }
  short* dst = &vT[(size_t)(bh * 256 + dt * 64 + r) * Sq + kt * 64 + c0];
  *(short8*)dst = o0;
  *(short8*)(dst + 8) = o1;
}

// ---------------- flash attention: 32x32 MFMA, dbuf pipeline, granule-major LDS
// 1D grid 512; 4 waves x 32 q-rows = 128 q-rows/block. KV tile = 32 keys.
// LDS layouts (16-B granules, all wave reads are contiguous 512-B blocks):
//   Ks slot = g*32 + key   (g = d-granule, d = g*8..g*8+7)
//   Vs slot = gk*256 + d   (gk = key-granule, keys gk*8..gk*8+7)
__global__ __launch_bounds__(256, 2) void k_attn(
    const short* __restrict__ qkv, const short* __restrict__ vT,
    short* __restrict__ attn)
{
  __shared__ short Ks[2][8192];   // 16 KB per buf
  __shared__ short Vs[2][8192];   // 16 KB per buf
  const int tid = threadIdx.x;
  const int w = tid >> 6, lane = tid & 63;
  const int l31 = lane & 31, hi = lane >> 5;
  const int id = blockIdx.x;
  // XCD-aware remap: 4 heads per XCD (id%8 ~ XCD under round-robin dispatch)
  const int bh = (id & 7) * 4 + ((id >> 3) & 3);
  const int qb0 = (id >> 5) * 128;
  const int b = bh >> 3, h = bh & 7;

  // Q as B-fragments: lane holds Q[qrow=l31][d = kc*16 + hi*8 + e]
  short8 qf[16];
  {
    const short* qbase = &qkv[(size_t)(b * Sq + qb0 + w * 32 + l31) * NQKV + h * 256 + hi * 8];
#pragma unroll
    for (int kc = 0; kc < 16; kc++) qf[kc] = *(const short8*)&qbase[kc * 16];
  }
  f32x16 o[8];
#pragma unroll
  for (int dt = 0; dt < 8; dt++) o[dt] = fz16();
  float m = -3e38f, l = 0.f;

  const size_t krow0 = (size_t)(b * Sq) * NQKV + 2048 + h * 256;
  const short* vbase = &vT[(size_t)bh * 256 * Sq];

  // ---- prologue: stage tile 0 ----
#pragma unroll
  for (int r = 0; r < 4; r++) {
    int G = r * 256 + tid;     // slot: holds K[key=G&31][d-granule G>>5]
    gload16(&qkv[krow0 + (size_t)(G & 31) * NQKV + (G >> 5) * 8],
            (char*)&Ks[0][0] + (r * 256 + w * 64) * 16);
  }
  {
    short8 v0[4];
#pragma unroll
    for (int r = 0; r < 4; r++) {
      int G = r * 256 + tid;
      v0[r] = *(const short8*)&vbase[(size_t)(G >> 2) * Sq + (G & 3) * 8];
    }
#pragma unroll
    for (int r = 0; r < 4; r++) {
      int G = r * 256 + tid;
      int s = ((G & 3) << 8) | (G >> 2);   // slot = gk*256 + d
      *(short8*)&Vs[0][s * 8] = v0[r];
    }
  }
  __syncthreads();

  int cur = 0;
  for (int kt = 0; kt < Sq / 32; kt++) {
    // ---- issue next tile's loads (K -> LDS[cur^1] direct, V -> regs) ----
    short8 vnext[4];
    if (kt + 1 < Sq / 32) {
#pragma unroll
      for (int r = 0; r < 4; r++) {
        int G = r * 256 + tid;
        gload16(&qkv[krow0 + (size_t)((kt + 1) * 32 + (G & 31)) * NQKV + (G >> 5) * 8],
                (char*)&Ks[cur ^ 1][0] + (r * 256 + w * 64) * 16);
      }
#pragma unroll
      for (int r = 0; r < 4; r++) {
        int G = r * 256 + tid;
        vnext[r] = *(const short8*)&vbase[(size_t)(G >> 2) * Sq + (kt + 1) * 32 + (G & 3) * 8];
      }
    }

    // ---- QK^T (swapped): sc = K_tile . Q^T -> [key][qrow], col = l31 ----
    f32x16 sc = fz16();
    __builtin_amdgcn_s_setprio(1);
#pragma unroll
    for (int kc = 0; kc < 16; kc++) {
      short8 ka = *(const short8*)&Ks[cur][((kc * 2 + hi) * 32 + l31) * 8];
      sc = __builtin_amdgcn_mfma_f32_32x32x16_bf16(ka, qf[kc], sc, 0, 0, 0);
    }
    __builtin_amdgcn_s_setprio(0);

    // ---- online softmax, in-register (scores in log2 domain) ----
    float t8[8];
#pragma unroll
    for (int e = 0; e < 8; e++) t8[e] = fmaxf(sc[e], sc[e + 8]);
#pragma unroll
    for (int e = 0; e < 4; e++) t8[e] = fmaxf(t8[e], t8[e + 4]);
    t8[0] = fmaxf(t8[0], t8[2]); t8[1] = fmaxf(t8[1], t8[3]);
    float pmax = fmaxf(t8[0], t8[1]);
    pmax = fmaxf(pmax, __shfl_xor(pmax, 32, 64));
    if (!__all(pmax <= m + 8.0f)) {          // defer-max (THR=8, log2 domain)
      float nm = fmaxf(m, pmax);
      float f = exp2a(m - nm);
      l *= f;
#pragma unroll
      for (int dt = 0; dt < 8; dt++)
#pragma unroll
        for (int e = 0; e < 16; e++) o[dt][e] *= f;
      m = nm;
    }
#pragma unroll
    for (int e = 0; e < 16; e++) sc[e] = exp2a(sc[e] - m);
    float r8[8];
#pragma unroll
    for (int e = 0; e < 8; e++) r8[e] = sc[e] + sc[e + 8];
#pragma unroll
    for (int e = 0; e < 4; e++) r8[e] = r8[e] + r8[e + 4];
    r8[0] += r8[2]; r8[1] += r8[3];
    float rs = r8[0] + r8[1];
    rs += __shfl_xor(rs, 32, 64);
    l += rs;

    // ---- P -> PV A-fragments in-register (cvt_pk + permlane32_swap) ----
    short8 pa[2];
    {
      unsigned x0 = cvtpk(sc[0], sc[1]);
      unsigned y0 = cvtpk(sc[4], sc[5]);
      unsigned x1 = cvtpk(sc[2], sc[3]);
      unsigned y1 = cvtpk(sc[6], sc[7]);
      plswap(x0, y0);
      plswap(x1, y1);
      i32x4 w0; w0[0] = x0; w0[1] = x1; w0[2] = y0; w0[3] = y1;
      pa[0] = __builtin_bit_cast(short8, w0);
      unsigned x2 = cvtpk(sc[8],  sc[9]);
      unsigned y2 = cvtpk(sc[12], sc[13]);
      unsigned x3 = cvtpk(sc[10], sc[11]);
      unsigned y3 = cvtpk(sc[14], sc[15]);
      plswap(x2, y2);
      plswap(x3, y3);
      i32x4 w1; w1[0] = x2; w1[1] = x3; w1[2] = y2; w1[3] = y3;
      pa[1] = __builtin_bit_cast(short8, w1);
    }

    // ---- PV: o[dt] += P . V ----
    __builtin_amdgcn_s_setprio(1);
#pragma unroll
    for (int dt = 0; dt < 8; dt++) {
#pragma unroll
      for (int ks = 0; ks < 2; ks++) {
        short8 vb = *(const short8*)&Vs[cur][(((ks * 2 + hi) << 8) | (dt * 32 + l31)) * 8];
        o[dt] = __builtin_amdgcn_mfma_f32_32x32x16_bf16(pa[ks], vb, o[dt], 0, 0, 0);
      }
    }
    __builtin_amdgcn_s_setprio(0);

    // ---- write prefetched V into LDS[cur^1], then single barrier ----
    if (kt + 1 < Sq / 32) {
#pragma unroll
      for (int r = 0; r < 4; r++) {
        int G = r * 256 + tid;
        int s = ((G & 3) << 8) | (G >> 2);
        *(short8*)&Vs[cur ^ 1][s * 8] = vnext[r];
      }
    }
    __syncthreads();
    cur ^= 1;
  }

  // ---- finalize: /l, store bf16 ----
  float linv = 1.0f / l;
  float li[16];
#pragma unroll
  for (int e = 0; e < 16; e++)
    li[e] = __shfl(linv, (e & 3) + 8 * (e >> 2) + 4 * hi, 64);
  short* orow = &attn[(size_t)(b * Sq + qb0 + w * 32) * HD + h * 256 + l31];
#pragma unroll
  for (int dt = 0; dt < 8; dt++)
#pragma unroll
    for (int e = 0; e < 16; e++)
      orow[(size_t)((e & 3) + 8 * (e >> 2) + 4 * hi) * HD + dt * 32] = f2bf(o[dt][e] * li[e]);
}

// ---------------- launch ----------------
extern "C" void kernel_launch(void* const* d_in, const int* in_sizes, int n_in,
                              void* d_out, int out_size, void* d_ws, size_t ws_size,
                              hipStream_t stream) {
  const float* x     = (const float*)d_in[0];
  const float* w_qkv = (const float*)d_in[1];
  const float* b_qkv = (const float*)d_in[2];
  const float* w_out = (const float*)d_in[3];
  const float* b_out = (const float*)d_in[4];
  float* out = (float*)d_out;

  char* ws = (char*)d_ws;
  short* qkv  = (short*)ws;                               // 100663296 B
  short* vT   = (short*)(ws + 100663296);                 // 33554432 B
  short* attn = (short*)(ws + 134217728);                 // 33554432 B
  short* xb   = (short*)(ws + 167772160);                 // 4194304 B
  short* wqb  = (short*)(ws + 171966464);                 // 3145728 B
  short* wob  = (short*)(ws + 175112192);                 // 1048576 B
  float* cost = (float*)(ws + 176160768);                 // 1048576 B
  float* sint = (float*)(ws + 177209344);                 // 1048576 B

  k_prep<<<dim3(17408), 256, 0, stream>>>(x, w_qkv, w_out, xb, wqb, wob, cost, sint);
  k_gemm<0, 128><<<dim3(NQKV / 128, MTOK / 128), 256, 0, stream>>>(
      xb, wqb, b_qkv, nullptr, qkv, MTOK, NQKV, Dq);
  k_rope<<<dim3(4096), 256, 0, stream>>>(qkv, cost, sint);
  k_vt<<<dim3(32, 4, 32), 256, 0, stream>>>(qkv, vT);
  k_attn<<<dim3(512), 256, 0, stream>>>(qkv, vT, attn);
  k_gemm<1, 64><<<dim3(Dq / 64, MTOK / 128), 256, 0, stream>>>(
      attn, wob, b_out, x, out, MTOK, Dq, HD);
}

// Round 7
// 339.001 us; speedup vs baseline: 1.1380x; 1.0044x over previous
//
#include <hip/hip_runtime.h>
#include <hip/hip_bf16.h>
#include <stdint.h>

#define Sq   2048
#define Dq   256
#define Hq   8
#define NQKV 6144          // 3*H*D
#define HD   2048          // H*D
#define MTOK 8192          // B*S

typedef __attribute__((ext_vector_type(8))) short short8;
typedef __attribute__((ext_vector_type(4))) float f32x4;
typedef __attribute__((ext_vector_type(16))) float f32x16;
typedef __attribute__((ext_vector_type(4))) int i32x4;

__device__ __forceinline__ float bf2f(short v) {
  union { float f; unsigned u; } x; x.u = ((unsigned)(unsigned short)v) << 16; return x.f;
}
__device__ __forceinline__ short f2bf(float f) {
  union { float f; unsigned u; } x; x.f = f;
  unsigned r = x.u + 0x7fffu + ((x.u >> 16) & 1u);
  return (short)(r >> 16);
}
// fp32 -> e4m3fn (OCP), RNE, saturate to 448
__device__ __forceinline__ unsigned f2e4m3(float f) {
  union { float f; unsigned u; } x; x.f = f;
  unsigned sign = (x.u >> 24) & 0x80u;
  float af = fabsf(f);
  if (af >= 448.f) return sign | 0x7Eu;
  if (af < 0.0009765625f) return sign;            // < 2^-10 rounds to 0
  int e = (int)((x.u >> 23) & 0xff) - 127;
  int L = (e < -6) ? -9 : e - 3;                  // lsb exponent
  union { float f; unsigned u; } s1, s2;
  s1.u = (unsigned)(127 - L) << 23;               // 2^-L
  s2.u = (unsigned)(127 + L) << 23;               // 2^L
  float t = rintf(af * s1.f);                     // RNE onto grid
  float val = t * s2.f;
  if (val == 0.f) return sign;
  union { float f; unsigned u; } y; y.f = val;
  int e2 = (int)((y.u >> 23) & 0xff) - 127;
  unsigned byte;
  if (e2 < -6) byte = (unsigned)(val * 512.f);    // subnormal: m * 2^-9
  else byte = ((unsigned)(e2 + 7) << 3) | ((y.u >> 20) & 7u);
  return sign | byte;
}
// global -> LDS direct (16B per lane); LDS dest is wave-uniform base + lane*16
__device__ __forceinline__ void gload16(const void* g, void* lds) {
  auto g1 = (const __attribute__((address_space(1))) int*)(uintptr_t)g;
  auto l3 = (__attribute__((address_space(3))) int*)(uintptr_t)lds;
  __builtin_amdgcn_global_load_lds(g1, l3, 16, 0, 0);
}
__device__ __forceinline__ float exp2a(float x) {   // D = 2^x
  float r; asm("v_exp_f32 %0, %1" : "=v"(r) : "v"(x)); return r;
}
__device__ __forceinline__ unsigned cvtpk(float lo, float hi) {
  unsigned r; asm("v_cvt_pk_bf16_f32 %0, %1, %2" : "=v"(r) : "v"(lo), "v"(hi)); return r;
}
__device__ __forceinline__ void plswap(unsigned &a, unsigned &b) {
  asm volatile("v_permlane32_swap_b32 %0, %1" : "+v"(a), "+v"(b));
}
__device__ __forceinline__ f32x16 fz16() {
  f32x16 z;
#pragma unroll
  for (int e = 0; e < 16; e++) z[e] = 0.f;
  return z;
}

// ---------------- prep: bf16 converts + rope tables (fp32 math) ----------------
__global__ __launch_bounds__(256) void k_prep(
    const float* __restrict__ x, const float* __restrict__ wqkv,
    const float* __restrict__ wout,
    short* __restrict__ xb, short* __restrict__ wqb, short* __restrict__ wob,
    float* __restrict__ cost, float* __restrict__ sint)
{
  long i = (long)blockIdx.x * 256 + threadIdx.x;
  const long n_x  = (long)MTOK * Dq;     // 2097152
  const long n_wq = (long)NQKV * Dq;     // 1572864
  const long n_wo = (long)Dq * HD;       // 524288
  const long n_tab = (long)Sq * 128;     // 262144
  if (i < n_x) { xb[i] = f2bf(x[i]); return; }
  i -= n_x;
  if (i < n_wq) { wqb[i] = f2bf(wqkv[i]); return; }
  i -= n_wq;
  if (i < n_wo) { wob[i] = f2bf(wout[i]); return; }
  i -= n_wo;
  if (i < n_tab) {
    int s = (int)(i >> 7), j = (int)(i & 127);
    float inv = __expf(-(float)j * (9.2103403720f / 128.0f));  // 10000^(-j/128)
    float a = (float)s * inv;
    cost[i] = cosf(a);
    sint[i] = sinf(a);
  }
}

// ---------------- GEMM: C[M,N] = A[M,K] * Bt[N,K]^T + bias (+resid) ----------------
template<int EPI, int BN>
__global__ __launch_bounds__(256, 2) void k_gemm(
    const short* __restrict__ A, const short* __restrict__ Bt,
    const float* __restrict__ bias, const float* __restrict__ resid,
    void* __restrict__ Cp, int M, int N, int K)
{
  constexpr int MI = (BN == 128) ? 4 : 2;   // 16-row tiles per wave
  constexpr int WRS = MI * 16;              // wave row span
  constexpr int BROUNDS = BN / 32;
  __shared__ short As[128 * 64];
  __shared__ short Bs[BN * 64];
  const int tid = threadIdx.x;
  const int w = tid >> 6, lane = tid & 63;
  const int grp = lane >> 4, l15 = lane & 15;
  const int wr = (BN == 128) ? (w >> 1) : w;
  const int wc = (BN == 128) ? (w & 1) : 0;
  const int m0 = blockIdx.y * 128, n0 = blockIdx.x * BN;

  f32x4 acc[MI][4];
#pragma unroll
  for (int i = 0; i < MI; i++)
#pragma unroll
    for (int j = 0; j < 4; j++) acc[i][j] = f32x4{0.f, 0.f, 0.f, 0.f};

  for (int kt = 0; kt < K; kt += 64) {
#pragma unroll
    for (int r = 0; r < 4; r++) {
      int G = r * 256 + tid;
      int row = G >> 3, gc = G & 7;
      gload16(A + (size_t)(m0 + row) * K + kt + gc * 8,
              (char*)As + (r * 256 + w * 64) * 16);
    }
#pragma unroll
    for (int r = 0; r < BROUNDS; r++) {
      int G = r * 256 + tid;
      int row = G >> 3, gc = G & 7;
      gload16(Bt + (size_t)(n0 + row) * K + kt + gc * 8,
              (char*)Bs + (r * 256 + w * 64) * 16);
    }
    __syncthreads();
#pragma unroll
    for (int kk = 0; kk < 2; kk++) {
      short8 af[MI], bf[4];
#pragma unroll
      for (int mi = 0; mi < MI; mi++) {
        int row = wr * WRS + mi * 16 + l15;
        af[mi] = *(const short8*)&As[row * 64 + kk * 32 + grp * 8];
      }
#pragma unroll
      for (int ni = 0; ni < 4; ni++) {
        int row = wc * 64 + ni * 16 + l15;
        bf[ni] = *(const short8*)&Bs[row * 64 + kk * 32 + grp * 8];
      }
#pragma unroll
      for (int mi = 0; mi < MI; mi++)
#pragma unroll
        for (int ni = 0; ni < 4; ni++)
          acc[mi][ni] = __builtin_amdgcn_mfma_f32_16x16x32_bf16(
              af[mi], bf[ni], acc[mi][ni], 0, 0, 0);
    }
    __syncthreads();
  }
#pragma unroll
  for (int mi = 0; mi < MI; mi++) {
#pragma unroll
    for (int ni = 0; ni < 4; ni++) {
      int colb = n0 + wc * 64 + ni * 16 + l15;
      float bv = bias[colb];
#pragma unroll
      for (int j = 0; j < 4; j++) {
        int row = m0 + wr * WRS + mi * 16 + grp * 4 + j;
        float v = acc[mi][ni][j] + bv;
        if (EPI == 0) {
          ((short*)Cp)[(size_t)row * N + colb] = f2bf(v);
        } else {
          size_t o = (size_t)row * N + colb;
          ((float*)Cp)[o] = v + resid[o];
        }
      }
    }
  }
}

// ---------------- rope + e4m3 pack, in-place into dead q-section ------------
// Block = 2 tokens. Reads q,k bf16; writes qf8 (bytes 0..2047) and kf8
// (bytes 2048..4095) of each token's 12288-B qkv row. Barrier between all
// reads and all writes makes the in-place overwrite race-free.
__global__ __launch_bounds__(256) void k_ropef8(
    short* __restrict__ qkv, const float* __restrict__ cost,
    const float* __restrict__ sint)
{
  int tt = blockIdx.x * 2 + (threadIdx.x >> 7);   // token
  int i = threadIdx.x & 127;
  int h = i >> 4, jv = i & 15;
  int s = tt & (Sq - 1);
  const short* qrow = qkv + (size_t)tt * NQKV + h * 256 + jv * 8;
  short8 q1 = *(const short8*)qrow;
  short8 q2 = *(const short8*)(qrow + 128);
  short8 k1 = *(const short8*)(qrow + 2048);
  short8 k2 = *(const short8*)(qrow + 2048 + 128);
  const float* cp = &cost[(size_t)s * 128 + jv * 8];
  const float* sp = &sint[(size_t)s * 128 + jv * 8];
  unsigned long oq1 = 0, oq2 = 0, ok1 = 0, ok2 = 0;
#pragma unroll
  for (int e = 0; e < 8; e++) {
    float c = cp[e], sn = sp[e];
    float a = bf2f(q1[e]), b2 = bf2f(q2[e]);
    oq1 |= (unsigned long)f2e4m3(a * c - b2 * sn) << (8 * e);
    oq2 |= (unsigned long)f2e4m3(a * sn + b2 * c) << (8 * e);
    float ka = bf2f(k1[e]), kb = bf2f(k2[e]);
    ok1 |= (unsigned long)f2e4m3(ka * c - kb * sn) << (8 * e);
    ok2 |= (unsigned long)f2e4m3(ka * sn + kb * c) << (8 * e);
  }
  __syncthreads();
  char* dst = (char*)qkv + (size_t)tt * 12288 + h * 256 + jv * 8;
  *(unsigned long*)(dst)              = oq1;
  *(unsigned long*)(dst + 128)        = oq2;
  *(unsigned long*)(dst + 2048)       = ok1;
  *(unsigned long*)(dst + 2048 + 128) = ok2;
}

// ---------------- V transpose: vT[bh][d][s] = v[b,s,h,d] ----------------
__global__ __launch_bounds__(256) void k_vt(
    const short* __restrict__ qkv, short* __restrict__ vT)
{
  __shared__ short t[64][72];
  int kt = blockIdx.x, dt = blockIdx.y, bh = blockIdx.z;
  int b = bh >> 3, h = bh & 7;
  int tid = threadIdx.x;
  int r = tid >> 2, c0 = (tid & 3) * 16;
  const short* src = &qkv[(size_t)(b * Sq + kt * 64 + r) * NQKV + 4096 + h * 256 + dt * 64 + c0];
  short8 v0 = *(const short8*)src;
  short8 v1 = *(const short8*)(src + 8);
#pragma unroll
  for (int e = 0; e < 8; e++) { t[r][c0 + e] = v0[e]; t[r][c0 + 8 + e] = v1[e]; }
  __syncthreads();
  short8 o0, o1;
#pragma unroll
  for (int e = 0; e < 8; e++) { o0[e] = t[c0 + e][r]; o1[e] = t[c0 + 8 + e][r]; }
  short* dst = &vT[(size_t)(bh * 256 + dt * 64 + r) * Sq + kt * 64 + c0];
  *(short8*)dst = o0;
  *(short8*)(dst + 8) = o1;
}

// ---------------- flash attention: fp8 QK^T, bf16 PV, full-DMA staging ------
// 1D grid 512; 4 waves x 32 q-rows. KV tile = 32 keys.
// Ks (fp8): slot = g*32 + key, g = d/16  -> 8 KB/buf, DMA 2 rounds
// Vs (bf16): slot = gk*256 + d, gk = key/8 -> 16 KB/buf, DMA 4 rounds
__global__ __launch_bounds__(256, 2) void k_attn(
    const char* __restrict__ qkvb, const short* __restrict__ vT,
    short* __restrict__ attn)
{
  __shared__ char  Ks[2][8192];
  __shared__ short Vs[2][8192];
  const int tid = threadIdx.x;
  const int w = tid >> 6, lane = tid & 63;
  const int l31 = lane & 31, hi = lane >> 5;
  const int id = blockIdx.x;
  const int bh = (id & 7) * 4 + ((id >> 3) & 3);   // XCD-aware remap
  const int qb0 = (id >> 5) * 128;
  const int b = bh >> 3, h = bh & 7;
  const float QS = 0.090168441f;                   // (1/16) * log2(e)

  // Q fp8 B-fragments: lane holds Q[qrow=l31][d = kc*16 + hi*8 + e]
  long qf[16];
  {
    const char* qbase = qkvb + (size_t)(b * Sq + qb0 + w * 32 + l31) * 12288 + h * 256 + hi * 8;
#pragma unroll
    for (int kc = 0; kc < 16; kc++) qf[kc] = *(const long*)(qbase + kc * 16);
  }
  f32x16 o[8];
#pragma unroll
  for (int dt = 0; dt < 8; dt++) o[dt] = fz16();
  float m = -3e38f, l = 0.f;

  const char* kbase = qkvb + (size_t)(b * Sq) * 12288 + 2048 + h * 256;
  const short* vbase = &vT[(size_t)bh * 256 * Sq];

  // ---- prologue: stage tile 0 ----
#pragma unroll
  for (int r = 0; r < 2; r++) {
    int G = r * 256 + tid;          // slot: key=G&31, g=G>>5
    gload16(kbase + (size_t)(G & 31) * 12288 + (G >> 5) * 16,
            (char*)&Ks[0][0] + (r * 256 + w * 64) * 16);
  }
#pragma unroll
  for (int r = 0; r < 4; r++) {
    int G = r * 256 + tid;          // slot: gk=G>>8, d=G&255
    gload16(vbase + (size_t)(G & 255) * Sq + (G >> 8) * 8,
            (char*)&Vs[0][0] + (r * 256 + w * 64) * 16);
  }
  __syncthreads();

  int cur = 0;
  for (int kt = 0; kt < Sq / 32; kt++) {
    // ---- issue next tile's DMA into buf^1 ----
    if (kt + 1 < Sq / 32) {
#pragma unroll
      for (int r = 0; r < 2; r++) {
        int G = r * 256 + tid;
        gload16(kbase + (size_t)((kt + 1) * 32 + (G & 31)) * 12288 + (G >> 5) * 16,
                (char*)&Ks[cur ^ 1][0] + (r * 256 + w * 64) * 16);
      }
#pragma unroll
      for (int r = 0; r < 4; r++) {
        int G = r * 256 + tid;
        gload16(vbase + (size_t)(G & 255) * Sq + (kt + 1) * 32 + (G >> 8) * 8,
                (char*)&Vs[cur ^ 1][0] + (r * 256 + w * 64) * 16);
      }
    }

    // ---- QK^T (swapped, fp8): sc = K_tile . Q^T -> [key][qrow], col = l31 ----
    f32x16 sc = fz16();
    __builtin_amdgcn_s_setprio(1);
#pragma unroll
    for (int kc = 0; kc < 16; kc++) {
      long ka = *(const long*)&Ks[cur][(kc * 32 + l31) * 16 + hi * 8];
      sc = __builtin_amdgcn_mfma_f32_32x32x16_fp8_fp8(ka, qf[kc], sc, 0, 0, 0);
    }
    __builtin_amdgcn_s_setprio(0);

    // ---- online softmax (raw scores; QS folded into the exp FMA) ----
    float t8[8];
#pragma unroll
    for (int e = 0; e < 8; e++) t8[e] = fmaxf(sc[e], sc[e + 8]);
#pragma unroll
    for (int e = 0; e < 4; e++) t8[e] = fmaxf(t8[e], t8[e + 4]);
    t8[0] = fmaxf(t8[0], t8[2]); t8[1] = fmaxf(t8[1], t8[3]);
    float pmax = fmaxf(t8[0], t8[1]);
    pmax = fmaxf(pmax, __shfl_xor(pmax, 32, 64));
    float pms = pmax * QS;
    if (!__all(pms <= m + 8.0f)) {          // defer-max (THR=8, log2 domain)
      float nm = fmaxf(m, pms);
      float f = exp2a(m - nm);
      l *= f;
#pragma unroll
      for (int dt = 0; dt < 8; dt++)
#pragma unroll
        for (int e = 0; e < 16; e++) o[dt][e] *= f;
      m = nm;
    }
#pragma unroll
    for (int e = 0; e < 16; e++) sc[e] = exp2a(fmaf(sc[e], QS, -m));
    float r8[8];
#pragma unroll
    for (int e = 0; e < 8; e++) r8[e] = sc[e] + sc[e + 8];
#pragma unroll
    for (int e = 0; e < 4; e++) r8[e] = r8[e] + r8[e + 4];
    r8[0] += r8[2]; r8[1] += r8[3];
    float rs = r8[0] + r8[1];
    rs += __shfl_xor(rs, 32, 64);
    l += rs;

    // ---- P -> PV A-fragments in-register (cvt_pk + permlane32_swap) ----
    short8 pa[2];
    {
      unsigned x0 = cvtpk(sc[0], sc[1]);
      unsigned y0 = cvtpk(sc[4], sc[5]);
      unsigned x1 = cvtpk(sc[2], sc[3]);
      unsigned y1 = cvtpk(sc[6], sc[7]);
      plswap(x0, y0);
      plswap(x1, y1);
      i32x4 w0; w0[0] = x0; w0[1] = x1; w0[2] = y0; w0[3] = y1;
      pa[0] = __builtin_bit_cast(short8, w0);
      unsigned x2 = cvtpk(sc[8],  sc[9]);
      unsigned y2 = cvtpk(sc[12], sc[13]);
      unsigned x3 = cvtpk(sc[10], sc[11]);
      unsigned y3 = cvtpk(sc[14], sc[15]);
      plswap(x2, y2);
      plswap(x3, y3);
      i32x4 w1; w1[0] = x2; w1[1] = x3; w1[2] = y2; w1[3] = y3;
      pa[1] = __builtin_bit_cast(short8, w1);
    }

    // ---- PV: o[dt] += P . V (bf16) ----
    __builtin_amdgcn_s_setprio(1);
#pragma unroll
    for (int dt = 0; dt < 8; dt++) {
#pragma unroll
      for (int ks = 0; ks < 2; ks++) {
        short8 vb = *(const short8*)&Vs[cur][(((ks * 2 + hi) << 8) | (dt * 32 + l31)) * 8];
        o[dt] = __builtin_amdgcn_mfma_f32_32x32x16_bf16(pa[ks], vb, o[dt], 0, 0, 0);
      }
    }
    __builtin_amdgcn_s_setprio(0);

    __syncthreads();
    cur ^= 1;
  }

  // ---- finalize: /l, store bf16 ----
  float linv = 1.0f / l;
  float li[16];
#pragma unroll
  for (int e = 0; e < 16; e++)
    li[e] = __shfl(linv, (e & 3) + 8 * (e >> 2) + 4 * hi, 64);
  short* orow = &attn[(size_t)(b * Sq + qb0 + w * 32) * HD + h * 256 + l31];
#pragma unroll
  for (int dt = 0; dt < 8; dt++)
#pragma unroll
    for (int e = 0; e < 16; e++)
      orow[(size_t)((e & 3) + 8 * (e >> 2) + 4 * hi) * HD + dt * 32] = f2bf(o[dt][e] * li[e]);
}

// ---------------- launch ----------------
extern "C" void kernel_launch(void* const* d_in, const int* in_sizes, int n_in,
                              void* d_out, int out_size, void* d_ws, size_t ws_size,
                              hipStream_t stream) {
  const float* x     = (const float*)d_in[0];
  const float* w_qkv = (const float*)d_in[1];
  const float* b_qkv = (const float*)d_in[2];
  const float* w_out = (const float*)d_in[3];
  const float* b_out = (const float*)d_in[4];
  float* out = (float*)d_out;

  char* ws = (char*)d_ws;
  short* qkv  = (short*)ws;                               // 100663296 B
  short* vT   = (short*)(ws + 100663296);                 // 33554432 B
  short* attn = (short*)(ws + 134217728);                 // 33554432 B
  short* xb   = (short*)(ws + 167772160);                 // 4194304 B
  short* wqb  = (short*)(ws + 171966464);                 // 3145728 B
  short* wob  = (short*)(ws + 175112192);                 // 1048576 B
  float* cost = (float*)(ws + 176160768);                 // 1048576 B
  float* sint = (float*)(ws + 177209344);                 // 1048576 B

  k_prep<<<dim3(17408), 256, 0, stream>>>(x, w_qkv, w_out, xb, wqb, wob, cost, sint);
  k_gemm<0, 128><<<dim3(NQKV / 128, MTOK / 128), 256, 0, stream>>>(
      xb, wqb, b_qkv, nullptr, qkv, MTOK, NQKV, Dq);
  k_ropef8<<<dim3(MTOK / 2), 256, 0, stream>>>(qkv, cost, sint);
  k_vt<<<dim3(32, 4, 32), 256, 0, stream>>>(qkv, vT);
  k_attn<<<dim3(512), 256, 0, stream>>>((const char*)qkv, vT, attn);
  k_gemm<1, 64><<<dim3(Dq / 64, MTOK / 128), 256, 0, stream>>>(
      attn, wob, b_out, x, out, MTOK, Dq, HD);
}

// Round 8
// 332.366 us; speedup vs baseline: 1.1607x; 1.0200x over previous
//
#include <hip/hip_runtime.h>
#include <hip/hip_bf16.h>
#include <stdint.h>

#define Sq   2048
#define Dq   256
#define Hq   8
#define NQKV 6144          // 3*H*D
#define HD   2048          // H*D
#define MTOK 8192          // B*S

typedef __attribute__((ext_vector_type(8))) short short8;
typedef __attribute__((ext_vector_type(4))) float f32x4;
typedef __attribute__((ext_vector_type(16))) float f32x16;
typedef __attribute__((ext_vector_type(4))) int i32x4;

__device__ __forceinline__ float bf2f(short v) {
  union { float f; unsigned u; } x; x.u = ((unsigned)(unsigned short)v) << 16; return x.f;
}
__device__ __forceinline__ short f2bf(float f) {
  union { float f; unsigned u; } x; x.f = f;
  unsigned r = x.u + 0x7fffu + ((x.u >> 16) & 1u);
  return (short)(r >> 16);
}
// fp32 -> e4m3fn (OCP), RNE, saturate to 448
__device__ __forceinline__ unsigned f2e4m3(float f) {
  union { float f; unsigned u; } x; x.f = f;
  unsigned sign = (x.u >> 24) & 0x80u;
  float af = fabsf(f);
  if (af >= 448.f) return sign | 0x7Eu;
  if (af < 0.0009765625f) return sign;            // < 2^-10 rounds to 0
  int e = (int)((x.u >> 23) & 0xff) - 127;
  int L = (e < -6) ? -9 : e - 3;                  // lsb exponent
  union { float f; unsigned u; } s1, s2;
  s1.u = (unsigned)(127 - L) << 23;               // 2^-L
  s2.u = (unsigned)(127 + L) << 23;               // 2^L
  float t = rintf(af * s1.f);                     // RNE onto grid
  float val = t * s2.f;
  if (val == 0.f) return sign;
  union { float f; unsigned u; } y; y.f = val;
  int e2 = (int)((y.u >> 23) & 0xff) - 127;
  unsigned byte;
  if (e2 < -6) byte = (unsigned)(val * 512.f);    // subnormal: m * 2^-9
  else byte = ((unsigned)(e2 + 7) << 3) | ((y.u >> 20) & 7u);
  return sign | byte;
}
// global -> LDS direct (16B per lane); LDS dest is wave-uniform base + lane*16
__device__ __forceinline__ void gload16(const void* g, void* lds) {
  auto g1 = (const __attribute__((address_space(1))) int*)(uintptr_t)g;
  auto l3 = (__attribute__((address_space(3))) int*)(uintptr_t)lds;
  __builtin_amdgcn_global_load_lds(g1, l3, 16, 0, 0);
}
__device__ __forceinline__ float exp2a(float x) {   // D = 2^x
  float r; asm("v_exp_f32 %0, %1" : "=v"(r) : "v"(x)); return r;
}
__device__ __forceinline__ unsigned cvtpk(float lo, float hi) {
  unsigned r; asm("v_cvt_pk_bf16_f32 %0, %1, %2" : "=v"(r) : "v"(lo), "v"(hi)); return r;
}
__device__ __forceinline__ void plswap(unsigned &a, unsigned &b) {
  asm volatile("v_permlane32_swap_b32 %0, %1" : "+v"(a), "+v"(b));
}
__device__ __forceinline__ f32x16 fz16() {
  f32x16 z;
#pragma unroll
  for (int e = 0; e < 16; e++) z[e] = 0.f;
  return z;
}

// ---------------- prep: bf16 converts + rope tables (fp32 math) ----------------
__global__ __launch_bounds__(256) void k_prep(
    const float* __restrict__ x, const float* __restrict__ wqkv,
    const float* __restrict__ wout,
    short* __restrict__ xb, short* __restrict__ wqb, short* __restrict__ wob,
    float* __restrict__ cost, float* __restrict__ sint)
{
  long i = (long)blockIdx.x * 256 + threadIdx.x;
  const long n_x  = (long)MTOK * Dq;     // 2097152
  const long n_wq = (long)NQKV * Dq;     // 1572864
  const long n_wo = (long)Dq * HD;       // 524288
  const long n_tab = (long)Sq * 128;     // 262144
  if (i < n_x) { xb[i] = f2bf(x[i]); return; }
  i -= n_x;
  if (i < n_wq) { wqb[i] = f2bf(wqkv[i]); return; }
  i -= n_wq;
  if (i < n_wo) { wob[i] = f2bf(wout[i]); return; }
  i -= n_wo;
  if (i < n_tab) {
    int s = (int)(i >> 7), j = (int)(i & 127);
    float inv = __expf(-(float)j * (9.2103403720f / 128.0f));  // 10000^(-j/128)
    float a = (float)s * inv;
    cost[i] = cosf(a);
    sint[i] = sinf(a);
  }
}

// ---------------- GEMM: C[M,N] = A[M,K] * Bt[N,K]^T + bias (+resid) ----------------
// EPI 0: bf16 out. EPI 1: fp32 out + resid.
// SWZ 0 (gemm0): 48 colb x 64 rowb, each XCD owns 6 col-panels, colb fastest.
// SWZ 1 (gemm1):  4 colb x 64 rowb, each XCD owns 8 row-panels, colb fastest.
template<int EPI, int BN, int SWZ>
__global__ __launch_bounds__(256, 2) void k_gemm(
    const short* __restrict__ A, const short* __restrict__ Bt,
    const float* __restrict__ bias, const float* __restrict__ resid,
    void* __restrict__ Cp, int M, int N, int K)
{
  constexpr int MI = (BN == 128) ? 4 : 2;   // 16-row tiles per wave
  constexpr int WRS = MI * 16;              // wave row span
  constexpr int BROUNDS = BN / 32;
  __shared__ short As[128 * 64];
  __shared__ short Bs[BN * 64];
  const int tid = threadIdx.x;
  const int w = tid >> 6, lane = tid & 63;
  const int grp = lane >> 4, l15 = lane & 15;
  const int wr = (BN == 128) ? (w >> 1) : w;
  const int wc = (BN == 128) ? (w & 1) : 0;
  int rowb, colb;
  {
    int id = blockIdx.x;
    int xcd = id & 7, idx = id >> 3;
    if (SWZ == 0) { colb = xcd * 6 + idx % 6; rowb = idx / 6; }
    else          { rowb = xcd * 8 + (idx >> 2); colb = idx & 3; }
  }
  const int m0 = rowb * 128, n0 = colb * BN;

  f32x4 acc[MI][4];
#pragma unroll
  for (int i = 0; i < MI; i++)
#pragma unroll
    for (int j = 0; j < 4; j++) acc[i][j] = f32x4{0.f, 0.f, 0.f, 0.f};

  for (int kt = 0; kt < K; kt += 64) {
#pragma unroll
    for (int r = 0; r < 4; r++) {
      int G = r * 256 + tid;
      int row = G >> 3, gc = G & 7;
      gload16(A + (size_t)(m0 + row) * K + kt + gc * 8,
              (char*)As + (r * 256 + w * 64) * 16);
    }
#pragma unroll
    for (int r = 0; r < BROUNDS; r++) {
      int G = r * 256 + tid;
      int row = G >> 3, gc = G & 7;
      gload16(Bt + (size_t)(n0 + row) * K + kt + gc * 8,
              (char*)Bs + (r * 256 + w * 64) * 16);
    }
    __syncthreads();
#pragma unroll
    for (int kk = 0; kk < 2; kk++) {
      short8 af[MI], bf[4];
#pragma unroll
      for (int mi = 0; mi < MI; mi++) {
        int row = wr * WRS + mi * 16 + l15;
        af[mi] = *(const short8*)&As[row * 64 + kk * 32 + grp * 8];
      }
#pragma unroll
      for (int ni = 0; ni < 4; ni++) {
        int row = wc * 64 + ni * 16 + l15;
        bf[ni] = *(const short8*)&Bs[row * 64 + kk * 32 + grp * 8];
      }
#pragma unroll
      for (int mi = 0; mi < MI; mi++)
#pragma unroll
        for (int ni = 0; ni < 4; ni++)
          acc[mi][ni] = __builtin_amdgcn_mfma_f32_16x16x32_bf16(
              af[mi], bf[ni], acc[mi][ni], 0, 0, 0);
    }
    __syncthreads();
  }
#pragma unroll
  for (int mi = 0; mi < MI; mi++) {
#pragma unroll
    for (int ni = 0; ni < 4; ni++) {
      int colc = n0 + wc * 64 + ni * 16 + l15;
      float bv = bias[colc];
#pragma unroll
      for (int j = 0; j < 4; j++) {
        int row = m0 + wr * WRS + mi * 16 + grp * 4 + j;
        float v = acc[mi][ni][j] + bv;
        if (EPI == 0) {
          ((short*)Cp)[(size_t)row * N + colc] = f2bf(v);
        } else {
          size_t o = (size_t)row * N + colc;
          ((float*)Cp)[o] = v + resid[o];
        }
      }
    }
  }
}

// ---------------- rope + e4m3 pack, in-place into dead q-section ------------
__global__ __launch_bounds__(256) void k_ropef8(
    short* __restrict__ qkv, const float* __restrict__ cost,
    const float* __restrict__ sint)
{
  int tt = blockIdx.x * 2 + (threadIdx.x >> 7);   // token
  int i = threadIdx.x & 127;
  int h = i >> 4, jv = i & 15;
  int s = tt & (Sq - 1);
  const short* qrow = qkv + (size_t)tt * NQKV + h * 256 + jv * 8;
  short8 q1 = *(const short8*)qrow;
  short8 q2 = *(const short8*)(qrow + 128);
  short8 k1 = *(const short8*)(qrow + 2048);
  short8 k2 = *(const short8*)(qrow + 2048 + 128);
  const float* cp = &cost[(size_t)s * 128 + jv * 8];
  const float* sp = &sint[(size_t)s * 128 + jv * 8];
  unsigned long oq1 = 0, oq2 = 0, ok1 = 0, ok2 = 0;
#pragma unroll
  for (int e = 0; e < 8; e++) {
    float c = cp[e], sn = sp[e];
    float a = bf2f(q1[e]), b2 = bf2f(q2[e]);
    oq1 |= (unsigned long)f2e4m3(a * c - b2 * sn) << (8 * e);
    oq2 |= (unsigned long)f2e4m3(a * sn + b2 * c) << (8 * e);
    float ka = bf2f(k1[e]), kb = bf2f(k2[e]);
    ok1 |= (unsigned long)f2e4m3(ka * c - kb * sn) << (8 * e);
    ok2 |= (unsigned long)f2e4m3(ka * sn + kb * c) << (8 * e);
  }
  __syncthreads();
  char* dst = (char*)qkv + (size_t)tt * 12288 + h * 256 + jv * 8;
  *(unsigned long*)(dst)              = oq1;
  *(unsigned long*)(dst + 128)        = oq2;
  *(unsigned long*)(dst + 2048)       = ok1;
  *(unsigned long*)(dst + 2048 + 128) = ok2;
}

// ---------------- V transpose: vT[bh][d][s] = v[b,s,h,d] ----------------
__global__ __launch_bounds__(256) void k_vt(
    const short* __restrict__ qkv, short* __restrict__ vT)
{
  __shared__ short t[64][72];
  int kt = blockIdx.x, dt = blockIdx.y, bh = blockIdx.z;
  int b = bh >> 3, h = bh & 7;
  int tid = threadIdx.x;
  int r = tid >> 2, c0 = (tid & 3) * 16;
  const short* src = &qkv[(size_t)(b * Sq + kt * 64 + r) * NQKV + 4096 + h * 256 + dt * 64 + c0];
  short8 v0 = *(const short8*)src;
  short8 v1 = *(const short8*)(src + 8);
#pragma unroll
  for (int e = 0; e < 8; e++) { t[r][c0 + e] = v0[e]; t[r][c0 + 8 + e] = v1[e]; }
  __syncthreads();
  short8 o0, o1;
#pragma unroll
  for (int e = 0; e < 8; e++) { o0[e] = t[c0 + e][r]; o1[e] = t[c0 + 8 + e][r]; }
  short* dst = &vT[(size_t)(bh * 256 + dt * 64 + r) * Sq + kt * 64 + c0];
  *(short8*)dst = o0;
  *(short8*)(dst + 8) = o1;
}

// ---------------- flash attention: fp8 QK^T, bf16 PV, full-DMA staging ------
// 1D grid 512; 4 waves x 32 q-rows. KV tile = 32 keys.
// Ks (fp8): slot = g*32 + key, g = d/16  -> 8 KB/buf, DMA 2 rounds
// Vs (bf16): slot = gk*256 + d, gk = key/8 -> 16 KB/buf, DMA 4 rounds
// DMA source pointers are hoisted per-lane and advanced by constants.
__global__ __launch_bounds__(256, 2) void k_attn(
    const char* __restrict__ qkvb, const short* __restrict__ vT,
    short* __restrict__ attn)
{
  __shared__ char  Ks[2][8192];
  __shared__ short Vs[2][8192];
  const int tid = threadIdx.x;
  const int w = tid >> 6, lane = tid & 63;
  const int l31 = lane & 31, hi = lane >> 5;
  const int id = blockIdx.x;
  const int bh = (id & 7) * 4 + ((id >> 3) & 3);   // XCD-aware remap
  const int qb0 = (id >> 5) * 128;
  const int b = bh >> 3, h = bh & 7;
  const float QS = 0.090168441f;                   // (1/16) * log2(e)

  // Q fp8 B-fragments: lane holds Q[qrow=l31][d = kc*16 + hi*8 + e]
  long qf[16];
  {
    const char* qbase = qkvb + (size_t)(b * Sq + qb0 + w * 32 + l31) * 12288 + h * 256 + hi * 8;
#pragma unroll
    for (int kc = 0; kc < 16; kc++) qf[kc] = *(const long*)(qbase + kc * 16);
  }
  f32x16 o[8];
#pragma unroll
  for (int dt = 0; dt < 8; dt++) o[dt] = fz16();
  float m = -3e38f, l = 0.f;

  // per-lane DMA source pointers (tile 0); advance by constants per tile
  const char* kp = qkvb + (size_t)(b * Sq) * 12288 + 2048 + h * 256
                 + (size_t)(tid & 31) * 12288 + (tid >> 5) * 16;
  const char* vp = (const char*)&vT[(size_t)bh * 256 * Sq] + (size_t)tid * (Sq * 2);

#define STAGE(BI) { \
    char* kD = (char*)Ks + (BI) * 8192  + w * 1024; \
    char* vD = (char*)Vs + (BI) * 16384 + w * 1024; \
    gload16(kp,       kD);          gload16(kp + 128, kD + 4096); \
    gload16(vp,       vD);          gload16(vp + 16,  vD + 4096); \
    gload16(vp + 32,  vD + 8192);   gload16(vp + 48,  vD + 12288); \
    kp += 32 * 12288; vp += 64; }

  // ---- prologue: stage tile 0 ----
  STAGE(0)
  __syncthreads();

  int cur = 0;
  for (int kt = 0; kt < Sq / 32; kt++) {
    // ---- issue next tile's DMA into buf^1 ----
    if (kt + 1 < Sq / 32) STAGE(cur ^ 1)

    // ---- QK^T (swapped, fp8): sc = K_tile . Q^T -> [key][qrow], col = l31 ----
    f32x16 sc = fz16();
    __builtin_amdgcn_s_setprio(1);
#pragma unroll
    for (int kc = 0; kc < 16; kc++) {
      long ka = *(const long*)&Ks[cur][(kc * 32 + l31) * 16 + hi * 8];
      sc = __builtin_amdgcn_mfma_f32_32x32x16_fp8_fp8(ka, qf[kc], sc, 0, 0, 0);
    }
    __builtin_amdgcn_s_setprio(0);

    // ---- online softmax (raw scores; QS folded into the exp FMA) ----
    float t8[8];
#pragma unroll
    for (int e = 0; e < 8; e++) t8[e] = fmaxf(sc[e], sc[e + 8]);
#pragma unroll
    for (int e = 0; e < 4; e++) t8[e] = fmaxf(t8[e], t8[e + 4]);
    t8[0] = fmaxf(t8[0], t8[2]); t8[1] = fmaxf(t8[1], t8[3]);
    float pmax = fmaxf(t8[0], t8[1]);
    pmax = fmaxf(pmax, __shfl_xor(pmax, 32, 64));
    float pms = pmax * QS;
    if (!__all(pms <= m + 8.0f)) {          // defer-max (THR=8, log2 domain)
      float nm = fmaxf(m, pms);
      float f = exp2a(m - nm);
      l *= f;
#pragma unroll
      for (int dt = 0; dt < 8; dt++)
#pragma unroll
        for (int e = 0; e < 16; e++) o[dt][e] *= f;
      m = nm;
    }
#pragma unroll
    for (int e = 0; e < 16; e++) sc[e] = exp2a(fmaf(sc[e], QS, -m));
    float r8[8];
#pragma unroll
    for (int e = 0; e < 8; e++) r8[e] = sc[e] + sc[e + 8];
#pragma unroll
    for (int e = 0; e < 4; e++) r8[e] = r8[e] + r8[e + 4];
    r8[0] += r8[2]; r8[1] += r8[3];
    float rs = r8[0] + r8[1];
    rs += __shfl_xor(rs, 32, 64);
    l += rs;

    // ---- P -> PV A-fragments in-register (cvt_pk + permlane32_swap) ----
    short8 pa[2];
    {
      unsigned x0 = cvtpk(sc[0], sc[1]);
      unsigned y0 = cvtpk(sc[4], sc[5]);
      unsigned x1 = cvtpk(sc[2], sc[3]);
      unsigned y1 = cvtpk(sc[6], sc[7]);
      plswap(x0, y0);
      plswap(x1, y1);
      i32x4 w0; w0[0] = x0; w0[1] = x1; w0[2] = y0; w0[3] = y1;
      pa[0] = __builtin_bit_cast(short8, w0);
      unsigned x2 = cvtpk(sc[8],  sc[9]);
      unsigned y2 = cvtpk(sc[12], sc[13]);
      unsigned x3 = cvtpk(sc[10], sc[11]);
      unsigned y3 = cvtpk(sc[14], sc[15]);
      plswap(x2, y2);
      plswap(x3, y3);
      i32x4 w1; w1[0] = x2; w1[1] = x3; w1[2] = y2; w1[3] = y3;
      pa[1] = __builtin_bit_cast(short8, w1);
    }

    // ---- PV: o[dt] += P . V (bf16) ----
    __builtin_amdgcn_s_setprio(1);
#pragma unroll
    for (int dt = 0; dt < 8; dt++) {
#pragma unroll
      for (int ks = 0; ks < 2; ks++) {
        short8 vb = *(const short8*)&Vs[cur][(((ks * 2 + hi) << 8) | (dt * 32 + l31)) * 8];
        o[dt] = __builtin_amdgcn_mfma_f32_32x32x16_bf16(pa[ks], vb, o[dt], 0, 0, 0);
      }
    }
    __builtin_amdgcn_s_setprio(0);

    __syncthreads();
    cur ^= 1;
  }
#undef STAGE

  // ---- finalize: /l, store bf16 ----
  float linv = 1.0f / l;
  float li[16];
#pragma unroll
  for (int e = 0; e < 16; e++)
    li[e] = __shfl(linv, (e & 3) + 8 * (e >> 2) + 4 * hi, 64);
  short* orow = &attn[(size_t)(b * Sq + qb0 + w * 32) * HD + h * 256 + l31];
#pragma unroll
  for (int dt = 0; dt < 8; dt++)
#pragma unroll
    for (int e = 0; e < 16; e++)
      orow[(size_t)((e & 3) + 8 * (e >> 2) + 4 * hi) * HD + dt * 32] = f2bf(o[dt][e] * li[e]);
}

// ---------------- launch ----------------
extern "C" void kernel_launch(void* const* d_in, const int* in_sizes, int n_in,
                              void* d_out, int out_size, void* d_ws, size_t ws_size,
                              hipStream_t stream) {
  const float* x     = (const float*)d_in[0];
  const float* w_qkv = (const float*)d_in[1];
  const float* b_qkv = (const float*)d_in[2];
  const float* w_out = (const float*)d_in[3];
  const float* b_out = (const float*)d_in[4];
  float* out = (float*)d_out;

  char* ws = (char*)d_ws;
  short* qkv  = (short*)ws;                               // 100663296 B
  short* vT   = (short*)(ws + 100663296);                 // 33554432 B
  short* attn = (short*)(ws + 134217728);                 // 33554432 B
  short* xb   = (short*)(ws + 167772160);                 // 4194304 B
  short* wqb  = (short*)(ws + 171966464);                 // 3145728 B
  short* wob  = (short*)(ws + 175112192);                 // 1048576 B
  float* cost = (float*)(ws + 176160768);                 // 1048576 B
  float* sint = (float*)(ws + 177209344);                 // 1048576 B

  k_prep<<<dim3(17408), 256, 0, stream>>>(x, w_qkv, w_out, xb, wqb, wob, cost, sint);
  k_gemm<0, 128, 0><<<dim3(3072), 256, 0, stream>>>(
      xb, wqb, b_qkv, nullptr, qkv, MTOK, NQKV, Dq);
  k_ropef8<<<dim3(MTOK / 2), 256, 0, stream>>>(qkv, cost, sint);
  k_vt<<<dim3(32, 4, 32), 256, 0, stream>>>(qkv, vT);
  k_attn<<<dim3(512), 256, 0, stream>>>((const char*)qkv, vT, attn);
  k_gemm<1, 64, 1><<<dim3(256), 256, 0, stream>>>(
      attn, wob, b_out, x, out, MTOK, Dq, HD);
}